// Round 6
// baseline (420.938 us; speedup 1.0000x reference)
//
#include <hip/hip_runtime.h>

// ---------------------------------------------------------------------------
// GraphSAGE VAE forward. Round 6: gemm23 fusion (x2 stays in LDS),
// degree-sorted gather permutation, hist merged into pack_cast. 12 dispatches.
// N=50000, E=800000, IN=256, HID=128, OUT=64. Mpad=50048.
//
//   layer1: Y1 = x @ [W1l|W1r]; x1 = bn(relu(agg(Y1[:,:128])/deg + b1 + Y1[:,128:]))
//   layer2: a2 = agg(x1)/deg;   x2 = bn(relu([a2|x1] @ [[W2l];[W2r]] + b2))
//   layer3: Y3 = x2 @ [W3l|W3r]; mz = agg(Y3[:,:128])/deg + b3 + Y3[:,128:]
//           z  = mz[:,:64] + exp(mz[:,64:]) * mean(eps,0)
//   dec:    h  = bn(relu(z @ Wd1 + bd1)) + x1;  out = h @ Wd2 + bd2   (f32 out)
// ---------------------------------------------------------------------------

typedef unsigned short u16;
typedef short bf16x8 __attribute__((ext_vector_type(8)));
typedef float f32x4  __attribute__((ext_vector_type(4)));

constexpr float BN_EPS = 1e-5f;

__device__ __forceinline__ u16 f2bf(float f) {          // RNE f32 -> bf16
    unsigned u = __float_as_uint(f);
    return (u16)((u + 0x7FFFu + ((u >> 16) & 1u)) >> 16);
}
__device__ __forceinline__ float bf2f(u16 h) {
    return __uint_as_float(((unsigned)h) << 16);
}
__device__ __forceinline__ void gl_lds16(const void* g, void* l) {
    __builtin_amdgcn_global_load_lds(
        (const __attribute__((address_space(1))) unsigned*)g,
        (__attribute__((address_space(3))) unsigned*)l, 16, 0, 0);
}

// Stage a [128 rows][KS] bf16 panel chunk (rows 0..127, k32 at k0) into 8KB LDS.
// Source k-slot XOR swizzle; LDS stays linear (both-sides rule).
template<int KS>
__device__ __forceinline__ void stage_panel(const u16* g, char* lb, int k0, int t) {
    const int sr   = t >> 2;
    const int sq   = (t & 3) ^ ((t >> 3) & 3);
    const int wave = t >> 6;
    gl_lds16(g + (size_t)sr * KS + k0 + sq * 8,        lb + wave * 1024);
    gl_lds16(g + (size_t)(sr + 64) * KS + k0 + sq * 8, lb + 4096 + wave * 1024);
}

// ---------------- CSR + degree-sort construction ----------------

// hist + weight-pack + x-cast in one launch (independent work, same grid)
__global__ void histpack(const int* __restrict__ dst, int E, int* __restrict__ deg,
                         const float* __restrict__ x,
                         const float* __restrict__ W1l, const float* __restrict__ W1r,
                         const float* __restrict__ W2l, const float* __restrict__ W2r,
                         const float* __restrict__ W3l, const float* __restrict__ W3r,
                         const float* __restrict__ Wd1, const float* __restrict__ Wd2,
                         u16* __restrict__ Bt1, u16* __restrict__ Bt2,
                         u16* __restrict__ Bt3, u16* __restrict__ Btd1,
                         u16* __restrict__ Btd2, u16* __restrict__ xb,
                         int N, int Mpad) {
    int idx = blockIdx.x * 256 + threadIdx.x;
    if (idx < E) atomicAdd(&deg[dst[idx]], 1);
    if (idx < 65536) {                       // Bt1: W(k,c)=c<128?W1l[k,c]:W1r[k,c-128]
        int c = idx >> 8, k = idx & 255;
        float v = (c < 128) ? W1l[k * 128 + c] : W1r[k * 128 + (c - 128)];
        Bt1[c * 256 + k] = f2bf(v);
    } else if (idx < 131072) {               // Bt2: W(k,c)=k<128?W2l[k,c]:W2r[k-128,c]
        int i2 = idx - 65536;
        int c = i2 >> 8, k = i2 & 255;
        float v = (k < 128) ? W2l[k * 256 + c] : W2r[(k - 128) * 256 + c];
        Bt2[c * 256 + k] = f2bf(v);
    } else if (idx < 196608) {               // Bt3: like Bt1 with W3
        int i2 = idx - 131072;
        int c = i2 >> 8, k = i2 & 255;
        float v = (c < 128) ? W3l[k * 128 + c] : W3r[k * 128 + (c - 128)];
        Bt3[c * 256 + k] = f2bf(v);
    } else if (idx < 204800) {               // Btd1: Wd1 is 64x128
        int i2 = idx - 196608;
        int c = i2 >> 6, k = i2 & 63;
        Btd1[i2] = f2bf(Wd1[k * 128 + c]);
    } else if (idx < 237568) {               // Btd2: Wd2 is 128x256
        int i2 = idx - 204800;
        int c = i2 >> 7, k = i2 & 127;
        Btd2[i2] = f2bf(Wd2[k * 256 + c]);
    }
    if (idx < Mpad * 64) {                   // x -> bf16, padded rows zeroed
        int row = idx >> 6, q = idx & 63;
        float4 v = make_float4(0.f, 0.f, 0.f, 0.f);
        if (row < N) v = *(const float4*)&x[(size_t)row * 256 + q * 4];
        ushort4 o;
        o.x = f2bf(v.x); o.y = f2bf(v.y); o.z = f2bf(v.z); o.w = f2bf(v.w);
        *(ushort4*)&xb[(size_t)row * 256 + q * 4] = o;
    }
}

// per-block deg sums + global degree histogram (64 clamped bins)
__global__ __launch_bounds__(256)
void scan_partial(const int* __restrict__ deg, int N, int* __restrict__ bsum,
                  int* __restrict__ bins) {
    __shared__ int sd[256];
    __shared__ int lbins[64];
    int i = blockIdx.x * 256 + threadIdx.x;
    int v = (i < N) ? deg[i] : 0;
    sd[threadIdx.x] = v;
    if (threadIdx.x < 64) lbins[threadIdx.x] = 0;
    __syncthreads();
    if (i < N) atomicAdd(&lbins[min(v, 63)], 1);
    for (int off = 128; off > 0; off >>= 1) {
        if (threadIdx.x < off) sd[threadIdx.x] += sd[threadIdx.x + off];
        __syncthreads();
    }
    if (threadIdx.x == 0) bsum[blockIdx.x] = sd[0];
    if (threadIdx.x < 64) {
        int c = lbins[threadIdx.x];
        if (c) atomicAdd(&bins[threadIdx.x], c);
    }
}

// exclusive scan of the 64 degree bins -> bincur (atomically bumped later)
__global__ void bin_scan(const int* __restrict__ bins, int* __restrict__ bincur) {
    __shared__ int sd[64];
    int t = threadIdx.x;
    int v = bins[t];
    sd[t] = v;
    __syncthreads();
    for (int off = 1; off < 64; off <<= 1) {
        int u = (t >= off) ? sd[t - off] : 0;
        __syncthreads();
        sd[t] += u;
        __syncthreads();
    }
    bincur[t] = sd[t] - v;   // exclusive prefix
}

// row_ptr/cursor/inv_deg + degree-sorted permutation fill
__global__ __launch_bounds__(256)
void scan_final2(const int* __restrict__ deg, const int* __restrict__ bsum,
                 int N, int E, int* __restrict__ row_ptr, int* __restrict__ cursor,
                 float* __restrict__ inv_deg, int* __restrict__ bincur,
                 int* __restrict__ perm) {
    __shared__ int sd[256];
    int t = threadIdx.x;
    int partial = 0;
    for (int j = t; j < blockIdx.x; j += 256) partial += bsum[j];
    sd[t] = partial;
    __syncthreads();
    for (int off = 128; off > 0; off >>= 1) {
        if (t < off) sd[t] += sd[t + off];
        __syncthreads();
    }
    int base = sd[0];
    __syncthreads();
    int i = blockIdx.x * 256 + t;
    int d = (i < N) ? deg[i] : 0;
    sd[t] = d;
    __syncthreads();
    for (int off = 1; off < 256; off <<= 1) {
        int u = (t >= off) ? sd[t - off] : 0;
        __syncthreads();
        sd[t] += u;
        __syncthreads();
    }
    if (i < N) {
        int excl = base + sd[t] - d;
        row_ptr[i] = excl;
        cursor[i]  = excl;
        inv_deg[i] = 1.0f / (float)max(d, 1);
        if (i == N - 1) row_ptr[N] = E;
        int pos = atomicAdd(&bincur[min(d, 63)], 1);
        perm[pos] = i;
    }
}

__global__ void fill_kernel(const int* __restrict__ src, const int* __restrict__ dst,
                            int E, int* __restrict__ cursor, int* __restrict__ csr) {
    int e = blockIdx.x * 256 + threadIdx.x;
    if (e < E) {
        int p = atomicAdd(&cursor[dst[e]], 1);
        csr[p] = src[e];
    }
}

// ---------------- bf16 MFMA GEMM (layer 1) ----------------

template<int K, int NC>
__global__ __launch_bounds__(256)
void mgemm(const u16* __restrict__ A, const u16* __restrict__ Bt,
           void* __restrict__ Cout, int M) {
    __shared__ char lds[32768];
    char* As0 = lds;
    char* As1 = lds + 8192;
    char* Bs0 = lds + 16384;
    char* Bs1 = lds + 24576;

    const int t = threadIdx.x;
    const int l = t & 63;
    const int wave = t >> 6;
    const int wr = wave >> 1, wc = wave & 1;
    const int lr = l & 15, kg = l >> 4;
    const int row0 = blockIdx.x * 128;
    const int col0 = blockIdx.y * 128;

    f32x4 acc[4][4];
    #pragma unroll
    for (int m = 0; m < 4; m++)
        #pragma unroll
        for (int n = 0; n < 4; n++)
            #pragma unroll
            for (int r = 0; r < 4; r++) acc[m][n][r] = 0.f;

    const u16* Ab = A  + (size_t)row0 * K;
    const u16* Bb = Bt + (size_t)col0 * K;

    stage_panel<K>(Ab, As0, 0, t);
    stage_panel<K>(Bb, Bs0, 0, t);
    __syncthreads();

    const int swz = (kg ^ ((lr >> 1) & 3)) << 4;
    constexpr int NT = K / 32;
    for (int ks = 0; ks < NT; ks++) {
        char* Ac = (ks & 1) ? As1 : As0;
        char* Bc = (ks & 1) ? Bs1 : Bs0;
        if (ks + 1 < NT) {
            stage_panel<K>(Ab, (ks & 1) ? As0 : As1, (ks + 1) * 32, t);
            stage_panel<K>(Bb, (ks & 1) ? Bs0 : Bs1, (ks + 1) * 32, t);
        }
        bf16x8 af[4], bfr[4];
        #pragma unroll
        for (int m = 0; m < 4; m++)
            af[m] = *(const bf16x8*)(Ac + wr * 4096 + m * 1024 + lr * 64 + swz);
        #pragma unroll
        for (int n = 0; n < 4; n++)
            bfr[n] = *(const bf16x8*)(Bc + wc * 4096 + n * 1024 + lr * 64 + swz);
        #pragma unroll
        for (int m = 0; m < 4; m++)
            #pragma unroll
            for (int n = 0; n < 4; n++)
                acc[m][n] = __builtin_amdgcn_mfma_f32_16x16x32_bf16(
                    af[m], bfr[n], acc[m][n], 0, 0, 0);
        __syncthreads();
    }

    const int colb = col0 + wc * 64;
    const int rowb = row0 + wr * 64;
    __syncthreads();

    char* rp = lds + wave * 4096;
    #pragma unroll
    for (int m = 0; m < 4; m++) {
        #pragma unroll
        for (int n = 0; n < 4; n++)
            #pragma unroll
            for (int r = 0; r < 4; r++) {
                int rl = kg * 4 + r, cl = n * 16 + lr;
                ((u16*)rp)[rl * 64 + cl] = f2bf(acc[m][n][r]);
            }
        u16* rph = (u16*)rp;
        #pragma unroll
        for (int hh = 0; hh < 2; hh++) {
            int rloc = hh * 8 + (l >> 3);
            int grow = rowb + m * 16 + rloc;
            bf16x8 v8 = *(bf16x8*)&rph[rloc * 64 + (l & 7) * 8];
            if (grow < M)
                *(bf16x8*)((u16*)Cout + (size_t)grow * NC + colb + (l & 7) * 8) = v8;
        }
    }
}

// ---------------- fused layer2+layer3 GEMM ----------------
// x2-tile (64x256) = bn(relu(catX @ Bt2^T + b2)) kept in LDS (bf16, slot-XOR),
// then Y3-tile = x2 @ Bt3^T. Bit-identical to the split path.

__global__ __launch_bounds__(256)
void gemm23(const u16* __restrict__ catX, const u16* __restrict__ Bt2,
            const u16* __restrict__ Bt3,
            const float* __restrict__ b2, const float* __restrict__ g2,
            const float* __restrict__ be2,
            u16* __restrict__ Y3, int M) {
    __shared__ char lds[73728];     // [0,8K) A dbuf | [8K,40K) B dbuf | [40K,72K) x2h
    char* Ad0 = lds;
    char* Ad1 = lds + 4096;
    char* Bd0 = lds + 8192;
    char* Bd1 = lds + 8192 + 16384;
    char* hb  = lds + 40960;        // [64 rows][512B], 16B slots, slot ^= row&7

    const int t = threadIdx.x;
    const int l = t & 63;
    const int wave = t >> 6;        // wave owns output cols wave*64..wave*64+63
    const int lr = l & 15, kg = l >> 4;
    const int row0 = blockIdx.x * 64;
    const int swz = (kg ^ ((lr >> 1) & 3)) << 4;
    const int sr = t >> 2;
    const int sq = (t & 3) ^ ((t >> 3) & 3);
    const float rs = rsqrtf(1.0f + BN_EPS);

    const u16* Ab = catX + (size_t)row0 * 256;

    auto stageA = [&](char* buf, int k0) {   // 64 rows x 32k = 4KB
        gl_lds16(Ab + (size_t)sr * 256 + k0 + sq * 8, buf + wave * 1024);
    };
    auto stageB = [&](const u16* Bt, char* buf, int k0) {  // 256 c-rows x 32k = 16KB
        #pragma unroll
        for (int q = 0; q < 4; q++)
            gl_lds16(Bt + (size_t)(q * 64 + sr) * 256 + k0 + sq * 8,
                     buf + q * 4096 + wave * 1024);
    };

    f32x4 acc[4][4];
    #pragma unroll
    for (int m = 0; m < 4; m++)
        #pragma unroll
        for (int n = 0; n < 4; n++)
            #pragma unroll
            for (int r = 0; r < 4; r++) acc[m][n][r] = 0.f;

    // ---- phase 1: x2 = bn(relu(catX @ Bt2^T + b2)) ----
    stageA(Ad0, 0);
    stageB(Bt2, Bd0, 0);
    __syncthreads();
    for (int ks = 0; ks < 8; ks++) {
        char* Ac = (ks & 1) ? Ad1 : Ad0;
        char* Bc = (ks & 1) ? Bd1 : Bd0;
        if (ks < 7) {
            stageA((ks & 1) ? Ad0 : Ad1, (ks + 1) * 32);
            stageB(Bt2, (ks & 1) ? Bd0 : Bd1, (ks + 1) * 32);
        }
        bf16x8 af[4], bfr[4];
        #pragma unroll
        for (int m = 0; m < 4; m++)
            af[m] = *(const bf16x8*)(Ac + m * 1024 + lr * 64 + swz);
        #pragma unroll
        for (int n = 0; n < 4; n++)
            bfr[n] = *(const bf16x8*)(Bc + wave * 4096 + n * 1024 + lr * 64 + swz);
        #pragma unroll
        for (int m = 0; m < 4; m++)
            #pragma unroll
            for (int n = 0; n < 4; n++)
                acc[m][n] = __builtin_amdgcn_mfma_f32_16x16x32_bf16(
                    af[m], bfr[n], acc[m][n], 0, 0, 0);
        __syncthreads();
    }

    // prefetch first Bt3 panel while epilogue-1 runs (Bd0 free after ks=6 consumers)
    stageB(Bt3, Bd0, 0);

    {   // epilogue-1: bn(relu(+b2)) -> hb (bf16, slot-XOR swizzled)
        float bia[4], gpr[4], bet[4];
        #pragma unroll
        for (int n = 0; n < 4; n++) {
            int c = wave * 64 + n * 16 + lr;
            bia[n] = b2[c];
            gpr[n] = g2[c] * rs;
            bet[n] = be2[c];
        }
        #pragma unroll
        for (int m = 0; m < 4; m++)
            #pragma unroll
            for (int n = 0; n < 4; n++)
                #pragma unroll
                for (int r = 0; r < 4; r++) {
                    int rl = m * 16 + kg * 4 + r;       // 0..63
                    int cl = wave * 64 + n * 16 + lr;   // 0..255
                    float v = acc[m][n][r] + bia[n];
                    v = fmaxf(v, 0.f) * gpr[n] + bet[n];
                    int slot = (cl >> 3) ^ (rl & 7);
                    ((u16*)(hb + rl * 512 + slot * 16))[cl & 7] = f2bf(v);
                }
    }
    __syncthreads();

    // ---- phase 2: Y3 = x2 @ Bt3^T ----
    #pragma unroll
    for (int m = 0; m < 4; m++)
        #pragma unroll
        for (int n = 0; n < 4; n++)
            #pragma unroll
            for (int r = 0; r < 4; r++) acc[m][n][r] = 0.f;

    for (int ks = 0; ks < 8; ks++) {
        char* Bc = (ks & 1) ? Bd1 : Bd0;
        if (ks < 7) stageB(Bt3, (ks & 1) ? Bd0 : Bd1, (ks + 1) * 32);
        bf16x8 af[4], bfr[4];
        #pragma unroll
        for (int m = 0; m < 4; m++) {
            int row = m * 16 + lr;
            int s = (ks * 4 + kg) ^ (row & 7);
            af[m] = *(const bf16x8*)(hb + row * 512 + s * 16);
        }
        #pragma unroll
        for (int n = 0; n < 4; n++)
            bfr[n] = *(const bf16x8*)(Bc + wave * 4096 + n * 1024 + lr * 64 + swz);
        #pragma unroll
        for (int m = 0; m < 4; m++)
            #pragma unroll
            for (int n = 0; n < 4; n++)
                acc[m][n] = __builtin_amdgcn_mfma_f32_16x16x32_bf16(
                    af[m], bfr[n], acc[m][n], 0, 0, 0);
        __syncthreads();
    }

    // epilogue-2: Y3 (bf16) via per-wave repack, coalesced 16B stores
    char* rp = lds + wave * 4096;
    #pragma unroll
    for (int m = 0; m < 4; m++) {
        #pragma unroll
        for (int n = 0; n < 4; n++)
            #pragma unroll
            for (int r = 0; r < 4; r++) {
                int rl = kg * 4 + r, cl = n * 16 + lr;
                ((u16*)rp)[rl * 64 + cl] = f2bf(acc[m][n][r]);
            }
        u16* rph = (u16*)rp;
        #pragma unroll
        for (int hh = 0; hh < 2; hh++) {
            int rloc = hh * 8 + (l >> 3);
            int grow = row0 + m * 16 + rloc;
            bf16x8 v8 = *(bf16x8*)&rph[rloc * 64 + (l & 7) * 8];
            if (grow < M)
                *(bf16x8*)&Y3[(size_t)grow * 256 + wave * 64 + (l & 7) * 8] = v8;
        }
    }
}

// ---------------- fused decoder (round-5, unchanged) ----------------

__global__ __launch_bounds__(256)
void dec_fused(const u16* __restrict__ zb, const u16* __restrict__ Btd1,
               const u16* __restrict__ Btd2, const float* __restrict__ bd1,
               const float* __restrict__ g3, const float* __restrict__ be3,
               const u16* __restrict__ x1, const float* __restrict__ bd2,
               float* __restrict__ out, int M) {
    __shared__ char lds[65536];
    const int t = threadIdx.x;
    const int l = t & 63;
    const int wave = t >> 6;
    const int wr = wave >> 1, wc = wave & 1;
    const int lr = l & 15, kg = l >> 4;
    const int row0 = blockIdx.x * 128;
    const float rs = rsqrtf(1.0f + BN_EPS);
    const int swz = (kg ^ ((lr >> 1) & 3)) << 4;
    char* hb = lds + 32768;

    stage_panel<64>(zb + (size_t)row0 * 64, lds,         0, t);
    stage_panel<64>(zb + (size_t)row0 * 64, lds + 8192, 32, t);
    stage_panel<64>(Btd1, lds + 16384,  0, t);
    stage_panel<64>(Btd1, lds + 24576, 32, t);
    __syncthreads();

    f32x4 acc[4][4];
    #pragma unroll
    for (int m = 0; m < 4; m++)
        #pragma unroll
        for (int n = 0; n < 4; n++)
            #pragma unroll
            for (int r = 0; r < 4; r++) acc[m][n][r] = 0.f;

    #pragma unroll
    for (int ks = 0; ks < 2; ks++) {
        char* Ac = lds + ks * 8192;
        char* Bc = lds + 16384 + ks * 8192;
        bf16x8 af[4], bfr[4];
        #pragma unroll
        for (int m = 0; m < 4; m++)
            af[m] = *(const bf16x8*)(Ac + wr * 4096 + m * 1024 + lr * 64 + swz);
        #pragma unroll
        for (int n = 0; n < 4; n++)
            bfr[n] = *(const bf16x8*)(Bc + wc * 4096 + n * 1024 + lr * 64 + swz);
        #pragma unroll
        for (int m = 0; m < 4; m++)
            #pragma unroll
            for (int n = 0; n < 4; n++)
                acc[m][n] = __builtin_amdgcn_mfma_f32_16x16x32_bf16(
                    af[m], bfr[n], acc[m][n], 0, 0, 0);
    }

    {   // epilogue-1: bn(relu(+bd1)) + x1 -> h (bf16, LDS, swizzled)
        float bia[4], gpr[4], bet[4];
        #pragma unroll
        for (int n = 0; n < 4; n++) {
            int c = wc * 64 + n * 16 + lr;
            bia[n] = bd1[c];
            gpr[n] = g3[c] * rs;
            bet[n] = be3[c];
        }
        #pragma unroll
        for (int m = 0; m < 4; m++)
            #pragma unroll
            for (int n = 0; n < 4; n++)
                #pragma unroll
                for (int r = 0; r < 4; r++) {
                    int rl = wr * 64 + m * 16 + kg * 4 + r;
                    int cl = wc * 64 + n * 16 + lr;
                    float v = acc[m][n][r] + bia[n];
                    v = fmaxf(v, 0.f) * gpr[n] + bet[n];
                    v += bf2f(x1[(size_t)(row0 + rl) * 256 + cl]);
                    int slot = (cl >> 3) ^ (rl & 7);
                    ((u16*)(hb + rl * 256 + slot * 16))[cl & 7] = f2bf(v);
                }
    }
    __syncthreads();

    for (int ch = 0; ch < 2; ch++) {
        const u16* Bb2 = Btd2 + ch * 16384;
        stage_panel<128>(Bb2, lds, 0, t);
        #pragma unroll
        for (int m = 0; m < 4; m++)
            #pragma unroll
            for (int n = 0; n < 4; n++)
                #pragma unroll
                for (int r = 0; r < 4; r++) acc[m][n][r] = 0.f;
        __syncthreads();

        for (int ks = 0; ks < 4; ks++) {
            char* Bc = lds + (ks & 1) * 8192;
            if (ks + 1 < 4)
                stage_panel<128>(Bb2, lds + (((ks & 1) ^ 1) * 8192), (ks + 1) * 32, t);
            bf16x8 af[4], bfr[4];
            #pragma unroll
            for (int m = 0; m < 4; m++) {
                int row = wr * 64 + m * 16 + lr;
                int s = (ks * 4 + kg) ^ (row & 7);
                af[m] = *(const bf16x8*)(hb + row * 256 + s * 16);
            }
            #pragma unroll
            for (int n = 0; n < 4; n++)
                bfr[n] = *(const bf16x8*)(Bc + wc * 4096 + n * 1024 + lr * 64 + swz);
            #pragma unroll
            for (int m = 0; m < 4; m++)
                #pragma unroll
                for (int n = 0; n < 4; n++)
                    acc[m][n] = __builtin_amdgcn_mfma_f32_16x16x32_bf16(
                        af[m], bfr[n], acc[m][n], 0, 0, 0);
            __syncthreads();
        }

        const int colb = ch * 128 + wc * 64;
        const int rowb = row0 + wr * 64;
        float b2v[4];
        #pragma unroll
        for (int n = 0; n < 4; n++) b2v[n] = bd2[colb + n * 16 + lr];
        char* rp = lds + wave * 4096;
        #pragma unroll
        for (int m = 0; m < 4; m++) {
            #pragma unroll
            for (int n = 0; n < 4; n++)
                #pragma unroll
                for (int r = 0; r < 4; r++)
                    ((float*)rp)[(kg * 4 + r) * 64 + n * 16 + lr] = acc[m][n][r] + b2v[n];
            float* rpf = (float*)rp;
            #pragma unroll
            for (int rr = 0; rr < 4; rr++) {
                int rloc = rr * 4 + kg;
                int grow = rowb + m * 16 + rloc;
                if (grow < M) {
                    f32x4 v4 = *(f32x4*)&rpf[rloc * 64 + lr * 4];
                    *(f32x4*)&out[(size_t)grow * 256 + colb + lr * 4] = v4;
                }
            }
        }
        __syncthreads();
    }
}

// ---------------- 16-lane-group aggregation (degree-sorted via perm) --------------

__global__ __launch_bounds__(256)
void agg1_kernel(const u16* __restrict__ Y1, const int* __restrict__ row_ptr,
                 const int* __restrict__ csr, const float* __restrict__ inv_deg,
                 const int* __restrict__ perm,
                 const float* __restrict__ b1, const float* __restrict__ g1,
                 const float* __restrict__ be1, u16* __restrict__ catX, int N) {
    int gid = (blockIdx.x * 256 + threadIdx.x) >> 4;
    int sub = threadIdx.x & 15;
    if (gid >= N) return;
    int g = perm[gid];
    int b = row_ptr[g], e = row_ptr[g + 1];
    const int off = sub * 8;
    float a[8] = {};
    int ee = b;
    for (; ee + 3 < e; ee += 4) {
        int j0 = csr[ee], j1 = csr[ee + 1], j2 = csr[ee + 2], j3 = csr[ee + 3];
        bf16x8 v0 = *(const bf16x8*)&Y1[(size_t)j0 * 256 + off];
        bf16x8 v1 = *(const bf16x8*)&Y1[(size_t)j1 * 256 + off];
        bf16x8 v2 = *(const bf16x8*)&Y1[(size_t)j2 * 256 + off];
        bf16x8 v3 = *(const bf16x8*)&Y1[(size_t)j3 * 256 + off];
        #pragma unroll
        for (int r = 0; r < 8; r++)
            a[r] += (bf2f((u16)v0[r]) + bf2f((u16)v1[r]))
                  + (bf2f((u16)v2[r]) + bf2f((u16)v3[r]));
    }
    for (; ee < e; ee++) {
        bf16x8 v0 = *(const bf16x8*)&Y1[(size_t)csr[ee] * 256 + off];
        #pragma unroll
        for (int r = 0; r < 8; r++) a[r] += bf2f((u16)v0[r]);
    }
    float id = inv_deg[g];
    bf16x8 u = *(const bf16x8*)&Y1[(size_t)g * 256 + 128 + off];
    const float rs = rsqrtf(1.0f + BN_EPS);
    bf16x8 o;
    #pragma unroll
    for (int r = 0; r < 8; r++) {
        int c = off + r;
        float v = a[r] * id + b1[c] + bf2f((u16)u[r]);
        v = fmaxf(v, 0.f);
        v = v * (g1[c] * rs) + be1[c];
        o[r] = (short)f2bf(v);
    }
    *(bf16x8*)&catX[(size_t)g * 256 + 128 + off] = o;
}

__global__ __launch_bounds__(256)
void agg2_kernel(const int* __restrict__ row_ptr, const int* __restrict__ csr,
                 const float* __restrict__ inv_deg, const int* __restrict__ perm,
                 u16* __restrict__ catX, int N) {
    int gid = (blockIdx.x * 256 + threadIdx.x) >> 4;
    int sub = threadIdx.x & 15;
    if (gid >= N) return;
    int g = perm[gid];
    int b = row_ptr[g], e = row_ptr[g + 1];
    const int off = sub * 8;
    float a[8] = {};
    int ee = b;
    for (; ee + 3 < e; ee += 4) {
        int j0 = csr[ee], j1 = csr[ee + 1], j2 = csr[ee + 2], j3 = csr[ee + 3];
        bf16x8 v0 = *(const bf16x8*)&catX[(size_t)j0 * 256 + 128 + off];
        bf16x8 v1 = *(const bf16x8*)&catX[(size_t)j1 * 256 + 128 + off];
        bf16x8 v2 = *(const bf16x8*)&catX[(size_t)j2 * 256 + 128 + off];
        bf16x8 v3 = *(const bf16x8*)&catX[(size_t)j3 * 256 + 128 + off];
        #pragma unroll
        for (int r = 0; r < 8; r++)
            a[r] += (bf2f((u16)v0[r]) + bf2f((u16)v1[r]))
                  + (bf2f((u16)v2[r]) + bf2f((u16)v3[r]));
    }
    for (; ee < e; ee++) {
        bf16x8 v0 = *(const bf16x8*)&catX[(size_t)csr[ee] * 256 + 128 + off];
        #pragma unroll
        for (int r = 0; r < 8; r++) a[r] += bf2f((u16)v0[r]);
    }
    float id = inv_deg[g];
    bf16x8 o;
    #pragma unroll
    for (int r = 0; r < 8; r++) o[r] = (short)f2bf(a[r] * id);
    *(bf16x8*)&catX[(size_t)g * 256 + off] = o;
}

__global__ __launch_bounds__(256)
void agg3_kernel(const u16* __restrict__ Y3, const int* __restrict__ row_ptr,
                 const int* __restrict__ csr, const float* __restrict__ inv_deg,
                 const int* __restrict__ perm,
                 const float* __restrict__ b3, const float* __restrict__ eps,
                 u16* __restrict__ z, int N) {
    int gid = (blockIdx.x * 256 + threadIdx.x) >> 4;
    int sub = threadIdx.x & 15;
    if (gid >= N) return;
    int g = perm[gid];
    int b = row_ptr[g], e = row_ptr[g + 1];
    const int off = sub * 8;

    // eps mean: lane covers channels sub*4..sub*4+3 (f32x4), sum over T=10
    f32x4 emv = {0.f, 0.f, 0.f, 0.f};
    #pragma unroll
    for (int t10 = 0; t10 < 10; t10++) {
        f32x4 v = *(const f32x4*)&eps[((size_t)t10 * N + g) * 64 + sub * 4];
        emv += v;
    }
    emv *= 0.1f;

    float a[8] = {};
    int ee = b;
    for (; ee + 3 < e; ee += 4) {
        int j0 = csr[ee], j1 = csr[ee + 1], j2 = csr[ee + 2], j3 = csr[ee + 3];
        bf16x8 v0 = *(const bf16x8*)&Y3[(size_t)j0 * 256 + off];
        bf16x8 v1 = *(const bf16x8*)&Y3[(size_t)j1 * 256 + off];
        bf16x8 v2 = *(const bf16x8*)&Y3[(size_t)j2 * 256 + off];
        bf16x8 v3 = *(const bf16x8*)&Y3[(size_t)j3 * 256 + off];
        #pragma unroll
        for (int r = 0; r < 8; r++)
            a[r] += (bf2f((u16)v0[r]) + bf2f((u16)v1[r]))
                  + (bf2f((u16)v2[r]) + bf2f((u16)v3[r]));
    }
    for (; ee < e; ee++) {
        bf16x8 v0 = *(const bf16x8*)&Y3[(size_t)csr[ee] * 256 + off];
        #pragma unroll
        for (int r = 0; r < 8; r++) a[r] += bf2f((u16)v0[r]);
    }
    float id = inv_deg[g];
    bf16x8 u = *(const bf16x8*)&Y3[(size_t)g * 256 + 128 + off];
    float mzv[8];
    #pragma unroll
    for (int r = 0; r < 8; r++)
        mzv[r] = a[r] * id + b3[off + r] + bf2f((u16)u[r]);

    const int wl = threadIdx.x & 63;
    const int wb = wl & ~15;
    const int s0 = wb + ((2 * sub) & 15);
    const int s1 = wb + ((2 * sub + 1) & 15);
    float em8[8];
    #pragma unroll
    for (int q = 0; q < 4; q++) {
        em8[q]     = __shfl(emv[q], s0);
        em8[4 + q] = __shfl(emv[q], s1);
    }
    float hi[8];
    #pragma unroll
    for (int r = 0; r < 8; r++) hi[r] = __shfl_xor(mzv[r], 8);

    if (sub < 8) {
        bf16x8 o;
        #pragma unroll
        for (int r = 0; r < 8; r++)
            o[r] = (short)f2bf(mzv[r] + expf(hi[r]) * em8[r]);
        *(bf16x8*)&z[(size_t)g * 64 + sub * 8] = o;
    }
}

// ---------------- launch ----------------

extern "C" void kernel_launch(void* const* d_in, const int* in_sizes, int n_in,
                              void* d_out, int out_size, void* d_ws, size_t ws_size,
                              hipStream_t stream) {
    const float* x    = (const float*)d_in[0];
    const int*   ei   = (const int*)d_in[1];
    const float* eps  = (const float*)d_in[2];
    const float* W1l  = (const float*)d_in[3];
    const float* b1   = (const float*)d_in[4];
    const float* W1r  = (const float*)d_in[5];
    const float* g1   = (const float*)d_in[6];
    const float* be1  = (const float*)d_in[7];
    const float* W2l  = (const float*)d_in[8];
    const float* b2   = (const float*)d_in[9];
    const float* W2r  = (const float*)d_in[10];
    const float* g2   = (const float*)d_in[11];
    const float* be2  = (const float*)d_in[12];
    const float* W3l  = (const float*)d_in[13];
    const float* b3   = (const float*)d_in[14];
    const float* W3r  = (const float*)d_in[15];
    const float* Wd1  = (const float*)d_in[16];
    const float* bd1  = (const float*)d_in[17];
    const float* g3   = (const float*)d_in[18];
    const float* be3  = (const float*)d_in[19];
    const float* Wd2  = (const float*)d_in[20];
    const float* bd2  = (const float*)d_in[21];

    const int Nn   = in_sizes[0] / 256;        // 50000
    const int E    = in_sizes[1] / 2;          // 800000
    const int Mpad = ((Nn + 127) / 128) * 128; // 50048
    const int* srcp = ei;
    const int* dstp = ei + E;
    const int nb = (Nn + 255) / 256;           // 196

    char* w = (char*)d_ws;
    auto alloc = [&](size_t bytes) -> void* {
        void* p = (void*)w;
        w += (bytes + 255) & ~(size_t)255;
        return p;
    };
    int*   deg     = (int*)  alloc((size_t)Nn * 4);
    int*   bins    = (int*)  alloc(64 * 4);     // directly after deg (one memset)
    int*   bincur  = (int*)  alloc(64 * 4);
    int*   perm    = (int*)  alloc((size_t)Nn * 4);
    int*   bsum    = (int*)  alloc((size_t)nb * 4);
    int*   row_ptr = (int*)  alloc((size_t)(Nn + 1) * 4);
    int*   cursor  = (int*)  alloc((size_t)Nn * 4);
    float* inv_deg = (float*)alloc((size_t)Nn * 4);
    int*   csr     = (int*)  alloc((size_t)E * 4);
    u16*   Bt1     = (u16*)  alloc(256 * 256 * 2);
    u16*   Bt2     = (u16*)  alloc(256 * 256 * 2);
    u16*   Bt3     = (u16*)  alloc(256 * 256 * 2);
    u16*   Btd1    = (u16*)  alloc(128 * 64 * 2);
    u16*   Btd2    = (u16*)  alloc(256 * 128 * 2);
    u16*   xb      = (u16*)  alloc((size_t)Mpad * 256 * 2);
    u16*   zb      = (u16*)  alloc((size_t)Mpad * 64 * 2);
    u16*   bufA    = (u16*)  alloc((size_t)Mpad * 256 * 2);  // Y1b
    u16*   bufB    = (u16*)  alloc((size_t)Mpad * 256 * 2);  // catXb = [a2 | x1]
    u16*   bufC    = (u16*)  alloc((size_t)Mpad * 256 * 2);  // Y3b
    if ((size_t)(w - (char*)d_ws) > ws_size) return;

    // zero deg + bins in one memset (bins allocated directly after deg's pad)
    size_t degpad = ((size_t)Nn * 4 + 255) & ~(size_t)255;
    hipMemsetAsync(deg, 0, degpad + 256, stream);

    histpack<<<(Mpad * 64 + 255) / 256, 256, 0, stream>>>(
        dstp, E, deg, x, W1l, W1r, W2l, W2r, W3l, W3r, Wd1, Wd2,
        Bt1, Bt2, Bt3, Btd1, Btd2, xb, Nn, Mpad);
    scan_partial<<<nb, 256, 0, stream>>>(deg, Nn, bsum, bins);
    bin_scan<<<1, 64, 0, stream>>>(bins, bincur);
    scan_final2<<<nb, 256, 0, stream>>>(deg, bsum, Nn, E, row_ptr, cursor,
                                        inv_deg, bincur, perm);
    fill_kernel<<<(E + 255) / 256, 256, 0, stream>>>(srcp, dstp, E, cursor, csr);

    dim3 g2c(Mpad / 128, 2);
    const int aggBlocks = (Nn + 15) / 16;

    // layer 1
    mgemm<256, 256><<<g2c, 256, 0, stream>>>(xb, Bt1, bufA, Mpad);
    agg1_kernel<<<aggBlocks, 256, 0, stream>>>(bufA, row_ptr, csr, inv_deg, perm,
                                               b1, g1, be1, bufB, Nn);
    // layer 2 + 3 (fused GEMMs)
    agg2_kernel<<<aggBlocks, 256, 0, stream>>>(row_ptr, csr, inv_deg, perm, bufB, Nn);
    gemm23<<<Mpad / 64, 256, 0, stream>>>(bufB, Bt2, Bt3, b2, g2, be2, bufC, Mpad);
    agg3_kernel<<<aggBlocks, 256, 0, stream>>>(bufC, row_ptr, csr, inv_deg, perm,
                                               b3, eps, zb, Nn);
    // fused decoder
    dec_fused<<<Mpad / 128, 256, 0, stream>>>(
        zb, Btd1, Btd2, bd1, g3, be3, /*x1=*/bufB + 128, bd2, (float*)d_out, Nn);
}

// Round 7
// 282.190 us; speedup vs baseline: 1.4917x; 1.4917x over previous
//
#include <hip/hip_runtime.h>

// ---------------------------------------------------------------------------
// GraphSAGE VAE forward. Round 7: round-6 minus degree-sort (atomic contention
// regression). Keeps gemm23 fusion, dec_fused, histpack merge. 11 dispatches.
// N=50000, E=800000, IN=256, HID=128, OUT=64. Mpad=50048.
//
//   layer1: Y1 = x @ [W1l|W1r]; x1 = bn(relu(agg(Y1[:,:128])/deg + b1 + Y1[:,128:]))
//   layer2: a2 = agg(x1)/deg;   x2 = bn(relu([a2|x1] @ [[W2l];[W2r]] + b2))
//   layer3: Y3 = x2 @ [W3l|W3r]; mz = agg(Y3[:,:128])/deg + b3 + Y3[:,128:]
//           z  = mz[:,:64] + exp(mz[:,64:]) * mean(eps,0)
//   dec:    h  = bn(relu(z @ Wd1 + bd1)) + x1;  out = h @ Wd2 + bd2   (f32 out)
// ---------------------------------------------------------------------------

typedef unsigned short u16;
typedef short bf16x8 __attribute__((ext_vector_type(8)));
typedef float f32x4  __attribute__((ext_vector_type(4)));

constexpr float BN_EPS = 1e-5f;

__device__ __forceinline__ u16 f2bf(float f) {          // RNE f32 -> bf16
    unsigned u = __float_as_uint(f);
    return (u16)((u + 0x7FFFu + ((u >> 16) & 1u)) >> 16);
}
__device__ __forceinline__ float bf2f(u16 h) {
    return __uint_as_float(((unsigned)h) << 16);
}
__device__ __forceinline__ void gl_lds16(const void* g, void* l) {
    __builtin_amdgcn_global_load_lds(
        (const __attribute__((address_space(1))) unsigned*)g,
        (__attribute__((address_space(3))) unsigned*)l, 16, 0, 0);
}

// Stage a [128 rows][KS] bf16 panel chunk (rows 0..127, k32 at k0) into 8KB LDS.
// Source k-slot XOR swizzle; LDS stays linear (both-sides rule).
template<int KS>
__device__ __forceinline__ void stage_panel(const u16* g, char* lb, int k0, int t) {
    const int sr   = t >> 2;
    const int sq   = (t & 3) ^ ((t >> 3) & 3);
    const int wave = t >> 6;
    gl_lds16(g + (size_t)sr * KS + k0 + sq * 8,        lb + wave * 1024);
    gl_lds16(g + (size_t)(sr + 64) * KS + k0 + sq * 8, lb + 4096 + wave * 1024);
}

// ---------------- CSR construction + prep ----------------

// hist + weight-pack + x-cast in one launch (independent work, same grid)
__global__ void histpack(const int* __restrict__ dst, int E, int* __restrict__ deg,
                         const float* __restrict__ x,
                         const float* __restrict__ W1l, const float* __restrict__ W1r,
                         const float* __restrict__ W2l, const float* __restrict__ W2r,
                         const float* __restrict__ W3l, const float* __restrict__ W3r,
                         const float* __restrict__ Wd1, const float* __restrict__ Wd2,
                         u16* __restrict__ Bt1, u16* __restrict__ Bt2,
                         u16* __restrict__ Bt3, u16* __restrict__ Btd1,
                         u16* __restrict__ Btd2, u16* __restrict__ xb,
                         int N, int Mpad) {
    int idx = blockIdx.x * 256 + threadIdx.x;
    if (idx < E) atomicAdd(&deg[dst[idx]], 1);
    if (idx < 65536) {                       // Bt1: W(k,c)=c<128?W1l[k,c]:W1r[k,c-128]
        int c = idx >> 8, k = idx & 255;
        float v = (c < 128) ? W1l[k * 128 + c] : W1r[k * 128 + (c - 128)];
        Bt1[c * 256 + k] = f2bf(v);
    } else if (idx < 131072) {               // Bt2: W(k,c)=k<128?W2l[k,c]:W2r[k-128,c]
        int i2 = idx - 65536;
        int c = i2 >> 8, k = i2 & 255;
        float v = (k < 128) ? W2l[k * 256 + c] : W2r[(k - 128) * 256 + c];
        Bt2[c * 256 + k] = f2bf(v);
    } else if (idx < 196608) {               // Bt3: like Bt1 with W3
        int i2 = idx - 131072;
        int c = i2 >> 8, k = i2 & 255;
        float v = (c < 128) ? W3l[k * 128 + c] : W3r[k * 128 + (c - 128)];
        Bt3[c * 256 + k] = f2bf(v);
    } else if (idx < 204800) {               // Btd1: Wd1 is 64x128
        int i2 = idx - 196608;
        int c = i2 >> 6, k = i2 & 63;
        Btd1[i2] = f2bf(Wd1[k * 128 + c]);
    } else if (idx < 237568) {               // Btd2: Wd2 is 128x256
        int i2 = idx - 204800;
        int c = i2 >> 7, k = i2 & 127;
        Btd2[i2] = f2bf(Wd2[k * 256 + c]);
    }
    if (idx < Mpad * 64) {                   // x -> bf16, padded rows zeroed
        int row = idx >> 6, q = idx & 63;
        float4 v = make_float4(0.f, 0.f, 0.f, 0.f);
        if (row < N) v = *(const float4*)&x[(size_t)row * 256 + q * 4];
        ushort4 o;
        o.x = f2bf(v.x); o.y = f2bf(v.y); o.z = f2bf(v.z); o.w = f2bf(v.w);
        *(ushort4*)&xb[(size_t)row * 256 + q * 4] = o;
    }
}

__global__ __launch_bounds__(256)
void scan_partial(const int* __restrict__ deg, int N, int* __restrict__ bsum) {
    __shared__ int sd[256];
    int i = blockIdx.x * 256 + threadIdx.x;
    int v = (i < N) ? deg[i] : 0;
    sd[threadIdx.x] = v;
    __syncthreads();
    for (int off = 128; off > 0; off >>= 1) {
        if (threadIdx.x < off) sd[threadIdx.x] += sd[threadIdx.x + off];
        __syncthreads();
    }
    if (threadIdx.x == 0) bsum[blockIdx.x] = sd[0];
}

// per-block exclusive scan; block base self-computed from raw bsum totals
__global__ __launch_bounds__(256)
void scan_final2(const int* __restrict__ deg, const int* __restrict__ bsum,
                 int N, int E, int* __restrict__ row_ptr, int* __restrict__ cursor,
                 float* __restrict__ inv_deg) {
    __shared__ int sd[256];
    int t = threadIdx.x;
    int partial = 0;
    for (int j = t; j < blockIdx.x; j += 256) partial += bsum[j];
    sd[t] = partial;
    __syncthreads();
    for (int off = 128; off > 0; off >>= 1) {
        if (t < off) sd[t] += sd[t + off];
        __syncthreads();
    }
    int base = sd[0];
    __syncthreads();
    int i = blockIdx.x * 256 + t;
    int d = (i < N) ? deg[i] : 0;
    sd[t] = d;
    __syncthreads();
    for (int off = 1; off < 256; off <<= 1) {
        int u = (t >= off) ? sd[t - off] : 0;
        __syncthreads();
        sd[t] += u;
        __syncthreads();
    }
    if (i < N) {
        int excl = base + sd[t] - d;
        row_ptr[i] = excl;
        cursor[i]  = excl;
        inv_deg[i] = 1.0f / (float)max(d, 1);
        if (i == N - 1) row_ptr[N] = E;
    }
}

__global__ void fill_kernel(const int* __restrict__ src, const int* __restrict__ dst,
                            int E, int* __restrict__ cursor, int* __restrict__ csr) {
    int e = blockIdx.x * 256 + threadIdx.x;
    if (e < E) {
        int p = atomicAdd(&cursor[dst[e]], 1);
        csr[p] = src[e];
    }
}

// ---------------- bf16 MFMA GEMM (layer 1) ----------------

template<int K, int NC>
__global__ __launch_bounds__(256)
void mgemm(const u16* __restrict__ A, const u16* __restrict__ Bt,
           void* __restrict__ Cout, int M) {
    __shared__ char lds[32768];
    char* As0 = lds;
    char* As1 = lds + 8192;
    char* Bs0 = lds + 16384;
    char* Bs1 = lds + 24576;

    const int t = threadIdx.x;
    const int l = t & 63;
    const int wave = t >> 6;
    const int wr = wave >> 1, wc = wave & 1;
    const int lr = l & 15, kg = l >> 4;
    const int row0 = blockIdx.x * 128;
    const int col0 = blockIdx.y * 128;

    f32x4 acc[4][4];
    #pragma unroll
    for (int m = 0; m < 4; m++)
        #pragma unroll
        for (int n = 0; n < 4; n++)
            #pragma unroll
            for (int r = 0; r < 4; r++) acc[m][n][r] = 0.f;

    const u16* Ab = A  + (size_t)row0 * K;
    const u16* Bb = Bt + (size_t)col0 * K;

    stage_panel<K>(Ab, As0, 0, t);
    stage_panel<K>(Bb, Bs0, 0, t);
    __syncthreads();

    const int swz = (kg ^ ((lr >> 1) & 3)) << 4;
    constexpr int NT = K / 32;
    for (int ks = 0; ks < NT; ks++) {
        char* Ac = (ks & 1) ? As1 : As0;
        char* Bc = (ks & 1) ? Bs1 : Bs0;
        if (ks + 1 < NT) {
            stage_panel<K>(Ab, (ks & 1) ? As0 : As1, (ks + 1) * 32, t);
            stage_panel<K>(Bb, (ks & 1) ? Bs0 : Bs1, (ks + 1) * 32, t);
        }
        bf16x8 af[4], bfr[4];
        #pragma unroll
        for (int m = 0; m < 4; m++)
            af[m] = *(const bf16x8*)(Ac + wr * 4096 + m * 1024 + lr * 64 + swz);
        #pragma unroll
        for (int n = 0; n < 4; n++)
            bfr[n] = *(const bf16x8*)(Bc + wc * 4096 + n * 1024 + lr * 64 + swz);
        #pragma unroll
        for (int m = 0; m < 4; m++)
            #pragma unroll
            for (int n = 0; n < 4; n++)
                acc[m][n] = __builtin_amdgcn_mfma_f32_16x16x32_bf16(
                    af[m], bfr[n], acc[m][n], 0, 0, 0);
        __syncthreads();
    }

    const int colb = col0 + wc * 64;
    const int rowb = row0 + wr * 64;
    __syncthreads();

    char* rp = lds + wave * 4096;
    #pragma unroll
    for (int m = 0; m < 4; m++) {
        #pragma unroll
        for (int n = 0; n < 4; n++)
            #pragma unroll
            for (int r = 0; r < 4; r++) {
                int rl = kg * 4 + r, cl = n * 16 + lr;
                ((u16*)rp)[rl * 64 + cl] = f2bf(acc[m][n][r]);
            }
        u16* rph = (u16*)rp;
        #pragma unroll
        for (int hh = 0; hh < 2; hh++) {
            int rloc = hh * 8 + (l >> 3);
            int grow = rowb + m * 16 + rloc;
            bf16x8 v8 = *(bf16x8*)&rph[rloc * 64 + (l & 7) * 8];
            if (grow < M)
                *(bf16x8*)((u16*)Cout + (size_t)grow * NC + colb + (l & 7) * 8) = v8;
        }
    }
}

// ---------------- fused layer2+layer3 GEMM ----------------
// x2-tile (64x256) = bn(relu(catX @ Bt2^T + b2)) kept in LDS (bf16, slot-XOR),
// then Y3-tile = x2 @ Bt3^T. Bit-identical to the split path.

__global__ __launch_bounds__(256)
void gemm23(const u16* __restrict__ catX, const u16* __restrict__ Bt2,
            const u16* __restrict__ Bt3,
            const float* __restrict__ b2, const float* __restrict__ g2,
            const float* __restrict__ be2,
            u16* __restrict__ Y3, int M) {
    __shared__ char lds[73728];     // [0,8K) A dbuf | [8K,40K) B dbuf | [40K,72K) x2h
    char* Ad0 = lds;
    char* Ad1 = lds + 4096;
    char* Bd0 = lds + 8192;
    char* Bd1 = lds + 8192 + 16384;
    char* hb  = lds + 40960;        // [64 rows][512B], 16B slots, slot ^= row&7

    const int t = threadIdx.x;
    const int l = t & 63;
    const int wave = t >> 6;        // wave owns output cols wave*64..wave*64+63
    const int lr = l & 15, kg = l >> 4;
    const int row0 = blockIdx.x * 64;
    const int swz = (kg ^ ((lr >> 1) & 3)) << 4;
    const int sr = t >> 2;
    const int sq = (t & 3) ^ ((t >> 3) & 3);
    const float rs = rsqrtf(1.0f + BN_EPS);

    const u16* Ab = catX + (size_t)row0 * 256;

    auto stageA = [&](char* buf, int k0) {   // 64 rows x 32k = 4KB
        gl_lds16(Ab + (size_t)sr * 256 + k0 + sq * 8, buf + wave * 1024);
    };
    auto stageB = [&](const u16* Bt, char* buf, int k0) {  // 256 c-rows x 32k = 16KB
        #pragma unroll
        for (int q = 0; q < 4; q++)
            gl_lds16(Bt + (size_t)(q * 64 + sr) * 256 + k0 + sq * 8,
                     buf + q * 4096 + wave * 1024);
    };

    f32x4 acc[4][4];
    #pragma unroll
    for (int m = 0; m < 4; m++)
        #pragma unroll
        for (int n = 0; n < 4; n++)
            #pragma unroll
            for (int r = 0; r < 4; r++) acc[m][n][r] = 0.f;

    // ---- phase 1: x2 = bn(relu(catX @ Bt2^T + b2)) ----
    stageA(Ad0, 0);
    stageB(Bt2, Bd0, 0);
    __syncthreads();
    for (int ks = 0; ks < 8; ks++) {
        char* Ac = (ks & 1) ? Ad1 : Ad0;
        char* Bc = (ks & 1) ? Bd1 : Bd0;
        if (ks < 7) {
            stageA((ks & 1) ? Ad0 : Ad1, (ks + 1) * 32);
            stageB(Bt2, (ks & 1) ? Bd0 : Bd1, (ks + 1) * 32);
        }
        bf16x8 af[4], bfr[4];
        #pragma unroll
        for (int m = 0; m < 4; m++)
            af[m] = *(const bf16x8*)(Ac + m * 1024 + lr * 64 + swz);
        #pragma unroll
        for (int n = 0; n < 4; n++)
            bfr[n] = *(const bf16x8*)(Bc + wave * 4096 + n * 1024 + lr * 64 + swz);
        #pragma unroll
        for (int m = 0; m < 4; m++)
            #pragma unroll
            for (int n = 0; n < 4; n++)
                acc[m][n] = __builtin_amdgcn_mfma_f32_16x16x32_bf16(
                    af[m], bfr[n], acc[m][n], 0, 0, 0);
        __syncthreads();
    }

    // prefetch first Bt3 panel while epilogue-1 runs
    stageB(Bt3, Bd0, 0);

    {   // epilogue-1: bn(relu(+b2)) -> hb (bf16, slot-XOR swizzled)
        float bia[4], gpr[4], bet[4];
        #pragma unroll
        for (int n = 0; n < 4; n++) {
            int c = wave * 64 + n * 16 + lr;
            bia[n] = b2[c];
            gpr[n] = g2[c] * rs;
            bet[n] = be2[c];
        }
        #pragma unroll
        for (int m = 0; m < 4; m++)
            #pragma unroll
            for (int n = 0; n < 4; n++)
                #pragma unroll
                for (int r = 0; r < 4; r++) {
                    int rl = m * 16 + kg * 4 + r;       // 0..63
                    int cl = wave * 64 + n * 16 + lr;   // 0..255
                    float v = acc[m][n][r] + bia[n];
                    v = fmaxf(v, 0.f) * gpr[n] + bet[n];
                    int slot = (cl >> 3) ^ (rl & 7);
                    ((u16*)(hb + rl * 512 + slot * 16))[cl & 7] = f2bf(v);
                }
    }
    __syncthreads();

    // ---- phase 2: Y3 = x2 @ Bt3^T ----
    #pragma unroll
    for (int m = 0; m < 4; m++)
        #pragma unroll
        for (int n = 0; n < 4; n++)
            #pragma unroll
            for (int r = 0; r < 4; r++) acc[m][n][r] = 0.f;

    for (int ks = 0; ks < 8; ks++) {
        char* Bc = (ks & 1) ? Bd1 : Bd0;
        if (ks < 7) stageB(Bt3, (ks & 1) ? Bd0 : Bd1, (ks + 1) * 32);
        bf16x8 af[4], bfr[4];
        #pragma unroll
        for (int m = 0; m < 4; m++) {
            int row = m * 16 + lr;
            int s = (ks * 4 + kg) ^ (row & 7);
            af[m] = *(const bf16x8*)(hb + row * 512 + s * 16);
        }
        #pragma unroll
        for (int n = 0; n < 4; n++)
            bfr[n] = *(const bf16x8*)(Bc + wave * 4096 + n * 1024 + lr * 64 + swz);
        #pragma unroll
        for (int m = 0; m < 4; m++)
            #pragma unroll
            for (int n = 0; n < 4; n++)
                acc[m][n] = __builtin_amdgcn_mfma_f32_16x16x32_bf16(
                    af[m], bfr[n], acc[m][n], 0, 0, 0);
        __syncthreads();
    }

    // epilogue-2: Y3 (bf16) via per-wave repack, coalesced 16B stores
    char* rp = lds + wave * 4096;
    #pragma unroll
    for (int m = 0; m < 4; m++) {
        #pragma unroll
        for (int n = 0; n < 4; n++)
            #pragma unroll
            for (int r = 0; r < 4; r++) {
                int rl = kg * 4 + r, cl = n * 16 + lr;
                ((u16*)rp)[rl * 64 + cl] = f2bf(acc[m][n][r]);
            }
        u16* rph = (u16*)rp;
        #pragma unroll
        for (int hh = 0; hh < 2; hh++) {
            int rloc = hh * 8 + (l >> 3);
            int grow = row0 + m * 16 + rloc;
            bf16x8 v8 = *(bf16x8*)&rph[rloc * 64 + (l & 7) * 8];
            if (grow < M)
                *(bf16x8*)&Y3[(size_t)grow * 256 + wave * 64 + (l & 7) * 8] = v8;
        }
    }
}

// ---------------- fused decoder ----------------

__global__ __launch_bounds__(256)
void dec_fused(const u16* __restrict__ zb, const u16* __restrict__ Btd1,
               const u16* __restrict__ Btd2, const float* __restrict__ bd1,
               const float* __restrict__ g3, const float* __restrict__ be3,
               const u16* __restrict__ x1, const float* __restrict__ bd2,
               float* __restrict__ out, int M) {
    __shared__ char lds[65536];
    const int t = threadIdx.x;
    const int l = t & 63;
    const int wave = t >> 6;
    const int wr = wave >> 1, wc = wave & 1;
    const int lr = l & 15, kg = l >> 4;
    const int row0 = blockIdx.x * 128;
    const float rs = rsqrtf(1.0f + BN_EPS);
    const int swz = (kg ^ ((lr >> 1) & 3)) << 4;
    char* hb = lds + 32768;

    stage_panel<64>(zb + (size_t)row0 * 64, lds,         0, t);
    stage_panel<64>(zb + (size_t)row0 * 64, lds + 8192, 32, t);
    stage_panel<64>(Btd1, lds + 16384,  0, t);
    stage_panel<64>(Btd1, lds + 24576, 32, t);
    __syncthreads();

    f32x4 acc[4][4];
    #pragma unroll
    for (int m = 0; m < 4; m++)
        #pragma unroll
        for (int n = 0; n < 4; n++)
            #pragma unroll
            for (int r = 0; r < 4; r++) acc[m][n][r] = 0.f;

    #pragma unroll
    for (int ks = 0; ks < 2; ks++) {
        char* Ac = lds + ks * 8192;
        char* Bc = lds + 16384 + ks * 8192;
        bf16x8 af[4], bfr[4];
        #pragma unroll
        for (int m = 0; m < 4; m++)
            af[m] = *(const bf16x8*)(Ac + wr * 4096 + m * 1024 + lr * 64 + swz);
        #pragma unroll
        for (int n = 0; n < 4; n++)
            bfr[n] = *(const bf16x8*)(Bc + wc * 4096 + n * 1024 + lr * 64 + swz);
        #pragma unroll
        for (int m = 0; m < 4; m++)
            #pragma unroll
            for (int n = 0; n < 4; n++)
                acc[m][n] = __builtin_amdgcn_mfma_f32_16x16x32_bf16(
                    af[m], bfr[n], acc[m][n], 0, 0, 0);
    }

    {   // epilogue-1: bn(relu(+bd1)) + x1 -> h (bf16, LDS, swizzled)
        float bia[4], gpr[4], bet[4];
        #pragma unroll
        for (int n = 0; n < 4; n++) {
            int c = wc * 64 + n * 16 + lr;
            bia[n] = bd1[c];
            gpr[n] = g3[c] * rs;
            bet[n] = be3[c];
        }
        #pragma unroll
        for (int m = 0; m < 4; m++)
            #pragma unroll
            for (int n = 0; n < 4; n++)
                #pragma unroll
                for (int r = 0; r < 4; r++) {
                    int rl = wr * 64 + m * 16 + kg * 4 + r;
                    int cl = wc * 64 + n * 16 + lr;
                    float v = acc[m][n][r] + bia[n];
                    v = fmaxf(v, 0.f) * gpr[n] + bet[n];
                    v += bf2f(x1[(size_t)(row0 + rl) * 256 + cl]);
                    int slot = (cl >> 3) ^ (rl & 7);
                    ((u16*)(hb + rl * 256 + slot * 16))[cl & 7] = f2bf(v);
                }
    }
    __syncthreads();

    for (int ch = 0; ch < 2; ch++) {
        const u16* Bb2 = Btd2 + ch * 16384;
        stage_panel<128>(Bb2, lds, 0, t);
        #pragma unroll
        for (int m = 0; m < 4; m++)
            #pragma unroll
            for (int n = 0; n < 4; n++)
                #pragma unroll
                for (int r = 0; r < 4; r++) acc[m][n][r] = 0.f;
        __syncthreads();

        for (int ks = 0; ks < 4; ks++) {
            char* Bc = lds + (ks & 1) * 8192;
            if (ks + 1 < 4)
                stage_panel<128>(Bb2, lds + (((ks & 1) ^ 1) * 8192), (ks + 1) * 32, t);
            bf16x8 af[4], bfr[4];
            #pragma unroll
            for (int m = 0; m < 4; m++) {
                int row = wr * 64 + m * 16 + lr;
                int s = (ks * 4 + kg) ^ (row & 7);
                af[m] = *(const bf16x8*)(hb + row * 256 + s * 16);
            }
            #pragma unroll
            for (int n = 0; n < 4; n++)
                bfr[n] = *(const bf16x8*)(Bc + wc * 4096 + n * 1024 + lr * 64 + swz);
            #pragma unroll
            for (int m = 0; m < 4; m++)
                #pragma unroll
                for (int n = 0; n < 4; n++)
                    acc[m][n] = __builtin_amdgcn_mfma_f32_16x16x32_bf16(
                        af[m], bfr[n], acc[m][n], 0, 0, 0);
            __syncthreads();
        }

        const int colb = ch * 128 + wc * 64;
        const int rowb = row0 + wr * 64;
        float b2v[4];
        #pragma unroll
        for (int n = 0; n < 4; n++) b2v[n] = bd2[colb + n * 16 + lr];
        char* rp = lds + wave * 4096;
        #pragma unroll
        for (int m = 0; m < 4; m++) {
            #pragma unroll
            for (int n = 0; n < 4; n++)
                #pragma unroll
                for (int r = 0; r < 4; r++)
                    ((float*)rp)[(kg * 4 + r) * 64 + n * 16 + lr] = acc[m][n][r] + b2v[n];
            float* rpf = (float*)rp;
            #pragma unroll
            for (int rr = 0; rr < 4; rr++) {
                int rloc = rr * 4 + kg;
                int grow = rowb + m * 16 + rloc;
                if (grow < M) {
                    f32x4 v4 = *(f32x4*)&rpf[rloc * 64 + lr * 4];
                    *(f32x4*)&out[(size_t)grow * 256 + colb + lr * 4] = v4;
                }
            }
        }
        __syncthreads();
    }
}

// ---------------- 16-lane-group aggregation (bf16x8 gathers, unroll x4) -----------

__global__ __launch_bounds__(256)
void agg1_kernel(const u16* __restrict__ Y1, const int* __restrict__ row_ptr,
                 const int* __restrict__ csr, const float* __restrict__ inv_deg,
                 const float* __restrict__ b1, const float* __restrict__ g1,
                 const float* __restrict__ be1, u16* __restrict__ catX, int N) {
    int g   = (blockIdx.x * 256 + threadIdx.x) >> 4;
    int sub = threadIdx.x & 15;
    if (g >= N) return;
    int b = row_ptr[g], e = row_ptr[g + 1];
    const int off = sub * 8;
    float a[8] = {};
    int ee = b;
    for (; ee + 3 < e; ee += 4) {
        int j0 = csr[ee], j1 = csr[ee + 1], j2 = csr[ee + 2], j3 = csr[ee + 3];
        bf16x8 v0 = *(const bf16x8*)&Y1[(size_t)j0 * 256 + off];
        bf16x8 v1 = *(const bf16x8*)&Y1[(size_t)j1 * 256 + off];
        bf16x8 v2 = *(const bf16x8*)&Y1[(size_t)j2 * 256 + off];
        bf16x8 v3 = *(const bf16x8*)&Y1[(size_t)j3 * 256 + off];
        #pragma unroll
        for (int r = 0; r < 8; r++)
            a[r] += (bf2f((u16)v0[r]) + bf2f((u16)v1[r]))
                  + (bf2f((u16)v2[r]) + bf2f((u16)v3[r]));
    }
    for (; ee < e; ee++) {
        bf16x8 v0 = *(const bf16x8*)&Y1[(size_t)csr[ee] * 256 + off];
        #pragma unroll
        for (int r = 0; r < 8; r++) a[r] += bf2f((u16)v0[r]);
    }
    float id = inv_deg[g];
    bf16x8 u = *(const bf16x8*)&Y1[(size_t)g * 256 + 128 + off];
    const float rs = rsqrtf(1.0f + BN_EPS);
    bf16x8 o;
    #pragma unroll
    for (int r = 0; r < 8; r++) {
        int c = off + r;
        float v = a[r] * id + b1[c] + bf2f((u16)u[r]);
        v = fmaxf(v, 0.f);
        v = v * (g1[c] * rs) + be1[c];
        o[r] = (short)f2bf(v);
    }
    *(bf16x8*)&catX[(size_t)g * 256 + 128 + off] = o;
}

__global__ __launch_bounds__(256)
void agg2_kernel(const int* __restrict__ row_ptr, const int* __restrict__ csr,
                 const float* __restrict__ inv_deg, u16* __restrict__ catX, int N) {
    int g   = (blockIdx.x * 256 + threadIdx.x) >> 4;
    int sub = threadIdx.x & 15;
    if (g >= N) return;
    int b = row_ptr[g], e = row_ptr[g + 1];
    const int off = sub * 8;
    float a[8] = {};
    int ee = b;
    for (; ee + 3 < e; ee += 4) {
        int j0 = csr[ee], j1 = csr[ee + 1], j2 = csr[ee + 2], j3 = csr[ee + 3];
        bf16x8 v0 = *(const bf16x8*)&catX[(size_t)j0 * 256 + 128 + off];
        bf16x8 v1 = *(const bf16x8*)&catX[(size_t)j1 * 256 + 128 + off];
        bf16x8 v2 = *(const bf16x8*)&catX[(size_t)j2 * 256 + 128 + off];
        bf16x8 v3 = *(const bf16x8*)&catX[(size_t)j3 * 256 + 128 + off];
        #pragma unroll
        for (int r = 0; r < 8; r++)
            a[r] += (bf2f((u16)v0[r]) + bf2f((u16)v1[r]))
                  + (bf2f((u16)v2[r]) + bf2f((u16)v3[r]));
    }
    for (; ee < e; ee++) {
        bf16x8 v0 = *(const bf16x8*)&catX[(size_t)csr[ee] * 256 + 128 + off];
        #pragma unroll
        for (int r = 0; r < 8; r++) a[r] += bf2f((u16)v0[r]);
    }
    float id = inv_deg[g];
    bf16x8 o;
    #pragma unroll
    for (int r = 0; r < 8; r++) o[r] = (short)f2bf(a[r] * id);
    *(bf16x8*)&catX[(size_t)g * 256 + off] = o;
}

__global__ __launch_bounds__(256)
void agg3_kernel(const u16* __restrict__ Y3, const int* __restrict__ row_ptr,
                 const int* __restrict__ csr, const float* __restrict__ inv_deg,
                 const float* __restrict__ b3, const float* __restrict__ eps,
                 u16* __restrict__ z, int N) {
    int g   = (blockIdx.x * 256 + threadIdx.x) >> 4;
    int sub = threadIdx.x & 15;
    if (g >= N) return;
    int b = row_ptr[g], e = row_ptr[g + 1];
    const int off = sub * 8;

    // eps mean: lane covers channels sub*4..sub*4+3 (f32x4), sum over T=10
    f32x4 emv = {0.f, 0.f, 0.f, 0.f};
    #pragma unroll
    for (int t10 = 0; t10 < 10; t10++) {
        f32x4 v = *(const f32x4*)&eps[((size_t)t10 * N + g) * 64 + sub * 4];
        emv += v;
    }
    emv *= 0.1f;

    float a[8] = {};
    int ee = b;
    for (; ee + 3 < e; ee += 4) {
        int j0 = csr[ee], j1 = csr[ee + 1], j2 = csr[ee + 2], j3 = csr[ee + 3];
        bf16x8 v0 = *(const bf16x8*)&Y3[(size_t)j0 * 256 + off];
        bf16x8 v1 = *(const bf16x8*)&Y3[(size_t)j1 * 256 + off];
        bf16x8 v2 = *(const bf16x8*)&Y3[(size_t)j2 * 256 + off];
        bf16x8 v3 = *(const bf16x8*)&Y3[(size_t)j3 * 256 + off];
        #pragma unroll
        for (int r = 0; r < 8; r++)
            a[r] += (bf2f((u16)v0[r]) + bf2f((u16)v1[r]))
                  + (bf2f((u16)v2[r]) + bf2f((u16)v3[r]));
    }
    for (; ee < e; ee++) {
        bf16x8 v0 = *(const bf16x8*)&Y3[(size_t)csr[ee] * 256 + off];
        #pragma unroll
        for (int r = 0; r < 8; r++) a[r] += bf2f((u16)v0[r]);
    }
    float id = inv_deg[g];
    bf16x8 u = *(const bf16x8*)&Y3[(size_t)g * 256 + 128 + off];
    float mzv[8];
    #pragma unroll
    for (int r = 0; r < 8; r++)
        mzv[r] = a[r] * id + b3[off + r] + bf2f((u16)u[r]);

    // redistribute em: lane sub<8 needs channels sub*8..sub*8+7
    const int wl = threadIdx.x & 63;
    const int wb = wl & ~15;
    const int s0 = wb + ((2 * sub) & 15);
    const int s1 = wb + ((2 * sub + 1) & 15);
    float em8[8];
    #pragma unroll
    for (int q = 0; q < 4; q++) {
        em8[q]     = __shfl(emv[q], s0);
        em8[4 + q] = __shfl(emv[q], s1);
    }
    float hi[8];
    #pragma unroll
    for (int r = 0; r < 8; r++) hi[r] = __shfl_xor(mzv[r], 8);

    if (sub < 8) {
        bf16x8 o;
        #pragma unroll
        for (int r = 0; r < 8; r++)
            o[r] = (short)f2bf(mzv[r] + expf(hi[r]) * em8[r]);
        *(bf16x8*)&z[(size_t)g * 64 + sub * 8] = o;
    }
}

// ---------------- launch ----------------

extern "C" void kernel_launch(void* const* d_in, const int* in_sizes, int n_in,
                              void* d_out, int out_size, void* d_ws, size_t ws_size,
                              hipStream_t stream) {
    const float* x    = (const float*)d_in[0];
    const int*   ei   = (const int*)d_in[1];
    const float* eps  = (const float*)d_in[2];
    const float* W1l  = (const float*)d_in[3];
    const float* b1   = (const float*)d_in[4];
    const float* W1r  = (const float*)d_in[5];
    const float* g1   = (const float*)d_in[6];
    const float* be1  = (const float*)d_in[7];
    const float* W2l  = (const float*)d_in[8];
    const float* b2   = (const float*)d_in[9];
    const float* W2r  = (const float*)d_in[10];
    const float* g2   = (const float*)d_in[11];
    const float* be2  = (const float*)d_in[12];
    const float* W3l  = (const float*)d_in[13];
    const float* b3   = (const float*)d_in[14];
    const float* W3r  = (const float*)d_in[15];
    const float* Wd1  = (const float*)d_in[16];
    const float* bd1  = (const float*)d_in[17];
    const float* g3   = (const float*)d_in[18];
    const float* be3  = (const float*)d_in[19];
    const float* Wd2  = (const float*)d_in[20];
    const float* bd2  = (const float*)d_in[21];

    const int Nn   = in_sizes[0] / 256;        // 50000
    const int E    = in_sizes[1] / 2;          // 800000
    const int Mpad = ((Nn + 127) / 128) * 128; // 50048
    const int* srcp = ei;
    const int* dstp = ei + E;
    const int nb = (Nn + 255) / 256;           // 196

    char* w = (char*)d_ws;
    auto alloc = [&](size_t bytes) -> void* {
        void* p = (void*)w;
        w += (bytes + 255) & ~(size_t)255;
        return p;
    };
    int*   deg     = (int*)  alloc((size_t)Nn * 4);
    int*   bsum    = (int*)  alloc((size_t)nb * 4);
    int*   row_ptr = (int*)  alloc((size_t)(Nn + 1) * 4);
    int*   cursor  = (int*)  alloc((size_t)Nn * 4);
    float* inv_deg = (float*)alloc((size_t)Nn * 4);
    int*   csr     = (int*)  alloc((size_t)E * 4);
    u16*   Bt1     = (u16*)  alloc(256 * 256 * 2);
    u16*   Bt2     = (u16*)  alloc(256 * 256 * 2);
    u16*   Bt3     = (u16*)  alloc(256 * 256 * 2);
    u16*   Btd1    = (u16*)  alloc(128 * 64 * 2);
    u16*   Btd2    = (u16*)  alloc(256 * 128 * 2);
    u16*   xb      = (u16*)  alloc((size_t)Mpad * 256 * 2);
    u16*   zb      = (u16*)  alloc((size_t)Mpad * 64 * 2);
    u16*   bufA    = (u16*)  alloc((size_t)Mpad * 256 * 2);  // Y1b
    u16*   bufB    = (u16*)  alloc((size_t)Mpad * 256 * 2);  // catXb = [a2 | x1]
    u16*   bufC    = (u16*)  alloc((size_t)Mpad * 256 * 2);  // Y3b
    if ((size_t)(w - (char*)d_ws) > ws_size) return;

    hipMemsetAsync(deg, 0, (size_t)Nn * 4, stream);
    histpack<<<(Mpad * 64 + 255) / 256, 256, 0, stream>>>(
        dstp, E, deg, x, W1l, W1r, W2l, W2r, W3l, W3r, Wd1, Wd2,
        Bt1, Bt2, Bt3, Btd1, Btd2, xb, Nn, Mpad);
    scan_partial<<<nb, 256, 0, stream>>>(deg, Nn, bsum);
    scan_final2<<<nb, 256, 0, stream>>>(deg, bsum, Nn, E, row_ptr, cursor, inv_deg);
    fill_kernel<<<(E + 255) / 256, 256, 0, stream>>>(srcp, dstp, E, cursor, csr);

    dim3 g2c(Mpad / 128, 2);
    const int aggBlocks = (Nn + 15) / 16;

    // layer 1
    mgemm<256, 256><<<g2c, 256, 0, stream>>>(xb, Bt1, bufA, Mpad);
    agg1_kernel<<<aggBlocks, 256, 0, stream>>>(bufA, row_ptr, csr, inv_deg,
                                               b1, g1, be1, bufB, Nn);
    // layer 2 + 3 (fused GEMMs)
    agg2_kernel<<<aggBlocks, 256, 0, stream>>>(row_ptr, csr, inv_deg, bufB, Nn);
    gemm23<<<Mpad / 64, 256, 0, stream>>>(bufB, Bt2, Bt3, b2, g2, be2, bufC, Mpad);
    agg3_kernel<<<aggBlocks, 256, 0, stream>>>(bufC, row_ptr, csr, inv_deg,
                                               b3, eps, zb, Nn);
    // fused decoder
    dec_fused<<<Mpad / 128, 256, 0, stream>>>(
        zb, Btd1, Btd2, bd1, g3, be3, /*x1=*/bufB + 128, bd2, (float*)d_out, Nn);
}